// Round 2
// baseline (26867.892 us; speedup 1.0000x reference)
//
#include <hip/hip_runtime.h>
#include <hip/hip_bf16.h>
#include <stdint.h>

#define BS 64
#define TT 512
#define FEAT 1024
#define HID 1024

__device__ __forceinline__ float sigmoidf_(float x){ return 1.0f/(1.0f + __expf(-x)); }

__device__ __forceinline__ unsigned short f2bf(float f){
    __hip_bfloat16 h = __float2bfloat16(f);
    return *reinterpret_cast<unsigned short*>(&h);
}
__device__ __forceinline__ float bf2f(unsigned short u){
    __hip_bfloat16 h = *reinterpret_cast<__hip_bfloat16*>(&u);
    return __bfloat162float(h);
}

// ---------------- Phase 1: [xz|xr|xh] = x @ [wz_x|wr_x|w_x] + bias ----------------
// M=32768 (b,t flat), N=3072 (z|r|h), K=1024. 128x64 tile, k-chunk 32, 256 threads,
// 8x4 register blocking. A stored transposed in LDS with XOR swizzle on the 8-col
// block index (c = (kk>>2)&3) -> staging stores are 2-way max (free), reads conflict-free.
__global__ __launch_bounds__(256) void p1_gemm(
    const float* __restrict__ x,
    const float* __restrict__ w_z, const float* __restrict__ w_r, const float* __restrict__ w,
    const float* __restrict__ bZ, const float* __restrict__ bR, const float* __restrict__ bH,
    float* __restrict__ xz32, float* __restrict__ xr32,
    unsigned short* __restrict__ xz16, unsigned short* __restrict__ xr16,
    float* __restrict__ xh, int use_bf)
{
    __shared__ float As[32][136];  // [kk][m-swizzled], 17.4 KB
    __shared__ float Bs[32][72];   // [kk][n], 9.2 KB

    const int m0   = blockIdx.x * 128;       // 0..32640
    const int n0g  = blockIdx.y * 64;        // 0..3008
    const int mat  = n0g >> 10;              // 0=z, 1=r, 2=h
    const int ncol = n0g & 1023;

    const float* Wm    = (mat==0) ? w_z : (mat==1) ? w_r : w;
    const float* Bbase = Wm + (size_t)HID*1024 + ncol;  // x-part rows [H, H+FEAT)
    const float* bias  = ((mat==0) ? bZ : (mat==1) ? bR : bH) + ncol;

    const int tid = threadIdx.x;
    const int tx = tid & 15, ty = tid >> 4;  // thread = 8 rows (ty) x 4 cols (tx)
    const int lm = tid >> 3;                 // 0..31
    const int lk = (tid & 7) * 4;            // 0..28

    float acc[8][4];
    #pragma unroll
    for (int i=0;i<8;i++)
        #pragma unroll
        for (int j=0;j<4;j++) acc[i][j] = 0.f;

    for (int k0 = 0; k0 < 1024; k0 += 32) {
        // stage A (transposed + swizzled): 128 rows x 32 k
        #pragma unroll
        for (int h = 0; h < 4; ++h) {
            const int m = lm + 32*h;
            float4 a = *(const float4*)(x + (size_t)(m0+m)*1024 + k0 + lk);
            const float av[4] = {a.x, a.y, a.z, a.w};
            #pragma unroll
            for (int i=0;i<4;i++) {
                const int kk  = lk + i;
                const int col = m ^ (((kk>>2)&3) << 3);
                As[kk][col] = av[i];
            }
        }
        // stage B: 32 k x 64 n
        {
            const int kk = tid >> 3;
            const int nq = (tid & 7) * 4;
            float4 b0 = *(const float4*)(Bbase + (size_t)(k0+kk)*1024 + nq);
            float4 b1 = *(const float4*)(Bbase + (size_t)(k0+kk)*1024 + nq + 32);
            *(float4*)&Bs[kk][nq]      = b0;
            *(float4*)&Bs[kk][nq + 32] = b1;
        }
        __syncthreads();
        #pragma unroll
        for (int kk = 0; kk < 32; ++kk) {
            const int ablk = (ty ^ ((kk>>2)&3)) << 3;
            float4 a0 = *(const float4*)&As[kk][ablk];
            float4 a1 = *(const float4*)&As[kk][ablk + 4];
            float4 b4 = *(const float4*)&Bs[kk][tx*4];
            const float av[8] = {a0.x,a0.y,a0.z,a0.w,a1.x,a1.y,a1.z,a1.w};
            const float bv[4] = {b4.x,b4.y,b4.z,b4.w};
            #pragma unroll
            for (int i=0;i<8;i++)
                #pragma unroll
                for (int j=0;j<4;j++)
                    acc[i][j] = fmaf(av[i], bv[j], acc[i][j]);
        }
        __syncthreads();
    }

    float4 bb = *(const float4*)(bias + tx*4);
    const float badd[4] = {bb.x, bb.y, bb.z, bb.w};
    #pragma unroll
    for (int i=0;i<8;i++) {
        const int m = m0 + ty*8 + i;
        const size_t off = (size_t)m*1024 + ncol + tx*4;
        float v[4];
        #pragma unroll
        for (int j=0;j<4;j++) v[j] = acc[i][j] + badd[j];
        if (mat == 2) {
            float4 o; o.x=v[0]; o.y=v[1]; o.z=v[2]; o.w=v[3];
            *(float4*)(xh + off) = o;
        } else if (!use_bf) {
            float* dst = (mat==0) ? xz32 : xr32;
            float4 o; o.x=v[0]; o.y=v[1]; o.z=v[2]; o.w=v[3];
            *(float4*)(dst + off) = o;
        } else {
            unsigned short* dst = (mat==0) ? xz16 : xr16;
            ushort4 u; u.x=f2bf(v[0]); u.y=f2bf(v[1]); u.z=f2bf(v[2]); u.w=f2bf(v[3]);
            *(ushort4*)(dst + off) = u;
        }
    }
}

// ---------------- transpose h_0 -> h_T[j][b] ----------------
__global__ __launch_bounds__(256) void tr_h0(const float* __restrict__ h0, float* __restrict__ hT)
{
    const int g = blockIdx.x*256 + threadIdx.x;   // 0..65535
    const int b = g >> 10, j = g & 1023;
    hT[j*64 + b] = h0[g];
}

// ---------------- per-step kernel 1: z_T, rh_T ----------------
// 256 WGs x 256 thr. WG owns 8 cols of the 2048 (z||r) col space; 4 waves split K by 256.
__global__ __launch_bounds__(256) void k_gates(
    const float* __restrict__ hT,
    const float* __restrict__ w_z, const float* __restrict__ w_r,
    const float* __restrict__ xz32, const float* __restrict__ xr32,
    const unsigned short* __restrict__ xz16, const unsigned short* __restrict__ xr16,
    float* __restrict__ zT, float* __restrict__ rhT, int t, int use_bf)
{
    __shared__ float part[4][8][64];
    const int wg   = blockIdx.x;                  // 0..255
    const int lane = threadIdx.x & 63;
    const int wv   = __builtin_amdgcn_readfirstlane(threadIdx.x >> 6);  // 0..3
    const bool isR = (wg >= 128);
    const float* W = isR ? w_r : w_z;             // h-part rows [0, H)
    const int ccol = (wg & 127) * 8;

    const float* wp = W  + (size_t)(wv*256)*1024 + ccol;
    const float* hp = hT + (size_t)(wv*256)*64   + lane;

    float acc[8] = {0,0,0,0,0,0,0,0};
    #pragma unroll 8
    for (int k = 0; k < 256; ++k) {
        const float hk = hp[(size_t)k*64];
        float4 wa = *(const float4*)(wp + (size_t)k*1024);
        float4 wb = *(const float4*)(wp + (size_t)k*1024 + 4);
        acc[0] = fmaf(hk, wa.x, acc[0]); acc[1] = fmaf(hk, wa.y, acc[1]);
        acc[2] = fmaf(hk, wa.z, acc[2]); acc[3] = fmaf(hk, wa.w, acc[3]);
        acc[4] = fmaf(hk, wb.x, acc[4]); acc[5] = fmaf(hk, wb.y, acc[5]);
        acc[6] = fmaf(hk, wb.z, acc[6]); acc[7] = fmaf(hk, wb.w, acc[7]);
    }
    #pragma unroll
    for (int c=0;c<8;c++) part[wv][c][lane] = acc[c];
    __syncthreads();

    #pragma unroll
    for (int e=0;e<2;e++) {
        const int o = threadIdx.x + e*256;        // 512 outputs
        const int c = o >> 6, b = o & 63;
        const float s = part[0][c][b] + part[1][c][b] + part[2][c][b] + part[3][c][b];
        const int j = ccol + c;
        const size_t xoff = ((size_t)b*TT + t)*1024 + j;
        if (!isR) {
            const float xv = use_bf ? bf2f(xz16[xoff]) : xz32[xoff];
            zT[j*64 + b] = sigmoidf_(s + xv);
        } else {
            const float xv = use_bf ? bf2f(xr16[xoff]) : xr32[xoff];
            rhT[j*64 + b] = sigmoidf_(s + xv) * hT[j*64 + b];
        }
    }
}

// ---------------- per-step kernel 2: hbar, h update, output ----------------
// 256 WGs x 256 thr. WG owns 4 cols of 1024; 4 waves split K by 256.
__global__ __launch_bounds__(256) void k_hbar(
    float* __restrict__ hT, const float* __restrict__ rhT, const float* __restrict__ zT,
    const float* __restrict__ w, float* __restrict__ out, int t, int is_last)
{
    __shared__ float part[4][4][64];
    const int wg   = blockIdx.x;
    const int lane = threadIdx.x & 63;
    const int wv   = __builtin_amdgcn_readfirstlane(threadIdx.x >> 6);
    const int c0   = wg * 4;

    const float* wp = w   + (size_t)(wv*256)*1024 + c0;   // w_h rows [0,H)
    const float* rp = rhT + (size_t)(wv*256)*64   + lane;

    float acc[4] = {0,0,0,0};
    #pragma unroll 8
    for (int k = 0; k < 256; ++k) {
        const float rk = rp[(size_t)k*64];
        float4 wa = *(const float4*)(wp + (size_t)k*1024);
        acc[0] = fmaf(rk, wa.x, acc[0]); acc[1] = fmaf(rk, wa.y, acc[1]);
        acc[2] = fmaf(rk, wa.z, acc[2]); acc[3] = fmaf(rk, wa.w, acc[3]);
    }
    #pragma unroll
    for (int c=0;c<4;c++) part[wv][c][lane] = acc[c];
    __syncthreads();

    const int o = threadIdx.x;                    // 256 outputs
    const int c = o >> 6, b = o & 63;
    const float s = part[0][c][b] + part[1][c][b] + part[2][c][b] + part[3][c][b];
    const int j = c0 + c;
    const size_t ooff = ((size_t)b*TT + t)*1024 + j;
    const float hb   = tanhf(s + out[ooff]);      // out currently holds xh[b][t][j]
    const float z    = zT[j*64 + b];
    const float hold = hT[j*64 + b];
    const float hn   = (1.f - z)*hold + z*hb;
    hT[j*64 + b] = hn;
    out[ooff]    = hn;
    if (is_last) out[(size_t)BS*TT*1024 + (size_t)b*1024 + j] = hn;
}

extern "C" void kernel_launch(void* const* d_in, const int* in_sizes, int n_in,
                              void* d_out, int out_size, void* d_ws, size_t ws_size,
                              hipStream_t stream)
{
    const float* x   = (const float*)d_in[0];
    const float* h0  = (const float*)d_in[1];
    const float* w_z = (const float*)d_in[2];
    const float* w_r = (const float*)d_in[3];
    const float* w   = (const float*)d_in[4];
    const float* bZ  = (const float*)d_in[5];
    const float* bR  = (const float*)d_in[6];
    const float* bH  = (const float*)d_in[7];
    float* out = (float*)d_out;

    const size_t nBT = (size_t)BS*TT*1024;        // 33,554,432
    const size_t need32 = (2*nBT + 3*65536) * 4;  // ~269 MB
    const int use_bf = (ws_size < need32) ? 1 : 0;

    char* wsb = (char*)d_ws;
    float *xz32 = nullptr, *xr32 = nullptr;
    unsigned short *xz16 = nullptr, *xr16 = nullptr;
    float *hT, *zT, *rhT;
    if (!use_bf) {
        xz32 = (float*)wsb;
        xr32 = xz32 + nBT;
        hT   = xr32 + nBT;
    } else {
        xz16 = (unsigned short*)wsb;
        xr16 = xz16 + nBT;
        hT   = (float*)(wsb + 2*nBT*sizeof(unsigned short));
    }
    zT  = hT + 65536;
    rhT = zT + 65536;

    p1_gemm<<<dim3(256,48), 256, 0, stream>>>(x, w_z, w_r, w, bZ, bR, bH,
                                              xz32, xr32, xz16, xr16, out, use_bf);
    tr_h0<<<256, 256, 0, stream>>>(h0, hT);
    for (int t = 0; t < TT; ++t) {
        k_gates<<<256, 256, 0, stream>>>(hT, w_z, w_r, xz32, xr32, xz16, xr16, zT, rhT, t, use_bf);
        k_hbar <<<256, 256, 0, stream>>>(hT, rhT, zT, w, out, t, (t == TT-1) ? 1 : 0);
    }
}